// Round 3
// baseline (516.945 us; speedup 1.0000x reference)
//
#include <hip/hip_runtime.h>
#include <hip/hip_bf16.h>

typedef __bf16 bf16;
typedef __bf16 bf16x4 __attribute__((ext_vector_type(4)));
typedef __bf16 bf16x8 __attribute__((ext_vector_type(8)));
typedef float f32x4 __attribute__((ext_vector_type(4)));

#define MFMA(a, b, c) __builtin_amdgcn_mfma_f32_16x16x32_bf16(a, b, c, 0, 0, 0)

__device__ inline f32x4 zf4() { return f32x4{0.f, 0.f, 0.f, 0.f}; }

constexpr int Bc = 2, Tc = 16, Hc = 56, Wc = 56, Cc = 128, NHc = 4, HDc = 32;
constexpr int VOL = 392;                 // 8*7*7 tokens per window
constexpr int STc = 4, SHc = 3, SWc = 3; // shift
constexpr int TWIN = 256;                // total windows (B * 128)
constexpr int MTOT = TWIN * VOL;         // 100352 tokens
constexpr int QSZ = TWIN * NHc * VOL * HDc; // elems per q/k/v ws array

__device__ inline bf16x8 zero8() {
    bf16x8 z;
#pragma unroll
    for (int j = 0; j < 8; ++j) z[j] = (bf16)0.0f;
    return z;
}

// ---------------------------------------------------------------------------
// Kernel 0: fp32 -> bf16 conversion (weights / biases / rel-pos-bias), x4 vec
// ---------------------------------------------------------------------------
__global__ void cvt_kernel(const float* __restrict__ src, bf16* __restrict__ dst,
                           int n4) {
    int i = blockIdx.x * blockDim.x + threadIdx.x;
    if (i < n4) {
        f32x4 v = *(const f32x4*)(src + (size_t)i * 4);
        bf16x4 o;
#pragma unroll
        for (int j = 0; j < 4; ++j) o[j] = (bf16)v[j];
        *(bf16x4*)(dst + (size_t)i * 4) = o;
    }
}

// ---------------------------------------------------------------------------
// Kernel 1: QKV projection. Gathers fp32 x rows in (shifted, window-
// partitioned) order (converting to bf16 in LDS), GEMM [64x128]@[128x384]^T
// per WG, writes q/k/v bf16 in [win][head][tok][32] layout. q pre-scaled.
// ---------------------------------------------------------------------------
__global__ __launch_bounds__(256, 2)
void qkv_kernel(const float* __restrict__ x, const bf16* __restrict__ wq,
                const bf16* __restrict__ bq, bf16* __restrict__ qws,
                bf16* __restrict__ kws, bf16* __restrict__ vws) {
    __shared__ bf16 As[64][136];  // 136 stride: 2-way-bank (free) for b128 reads
    __shared__ bf16 Cs[64][392];  // only cols 0..383 used
    const int tid = threadIdx.x;
    const int m0 = blockIdx.x * 64;

    // stage A: gather 64 window-token rows (roll + partition fused), cvt bf16
    for (int idx = tid; idx < 64 * 32; idx += 256) {
        int r = idx >> 5, c = idx & 31;   // c: 4-float chunk
        int g = m0 + r;
        int win = g / VOL, tok = g % VOL;
        int b = win >> 7, wi = win & 127;
        int wt_i = wi >> 6, wh_i = (wi >> 3) & 7, ww_i = wi & 7;
        int tt = tok / 49, r2 = tok % 49;
        int hh = r2 / 7, ww2 = r2 % 7;
        int t = wt_i * 8 + tt + STc; if (t >= Tc) t -= Tc;
        int h = wh_i * 7 + hh + SHc; if (h >= Hc) h -= Hc;
        int w = ww_i * 7 + ww2 + SWc; if (w >= Wc) w -= Wc;
        const float* src = x + (size_t)(((b * Tc + t) * Hc + h) * Wc + w) * Cc + c * 4;
        f32x4 v = *(const f32x4*)src;
        bf16x4 o;
#pragma unroll
        for (int j = 0; j < 4; ++j) o[j] = (bf16)v[j];
        *(bf16x4*)(&As[r][c * 4]) = o;
    }
    __syncthreads();

    const int wid = tid >> 6, lane = tid & 63;
    const int quad = lane >> 4, l15 = lane & 15;
    const int nbase = wid * 96;  // each wave: 6 n-tiles (96 cols) x 64 rows

    f32x4 acc[4][6];
#pragma unroll
    for (int ms = 0; ms < 4; ++ms)
#pragma unroll
        for (int nt = 0; nt < 6; ++nt) acc[ms][nt] = zf4();

#pragma unroll
    for (int ko = 0; ko < 4; ++ko) {
        bf16x8 af[4];
#pragma unroll
        for (int ms = 0; ms < 4; ++ms)
            af[ms] = *(const bf16x8*)(&As[ms * 16 + l15][ko * 32 + quad * 8]);
#pragma unroll
        for (int nt = 0; nt < 6; ++nt) {
            int n = nbase + nt * 16 + l15;
            bf16x8 bfrag = *(const bf16x8*)(wq + (size_t)n * Cc + ko * 32 + quad * 8);
#pragma unroll
            for (int ms = 0; ms < 4; ++ms)
                acc[ms][nt] = MFMA(af[ms], bfrag, acc[ms][nt]);
        }
    }

    float bcol[6];
#pragma unroll
    for (int nt = 0; nt < 6; ++nt) bcol[nt] = (float)bq[nbase + nt * 16 + l15];

#pragma unroll
    for (int nt = 0; nt < 6; ++nt) {
        int col = nbase + nt * 16 + l15;
        float scale = (col < 128) ? 0.17677669529663687f : 1.0f;  // 1/sqrt(32) on q
#pragma unroll
        for (int ms = 0; ms < 4; ++ms)
#pragma unroll
            for (int r = 0; r < 4; ++r) {
                int row = ms * 16 + quad * 4 + r;
                Cs[row][col] = (bf16)((acc[ms][nt][r] + bcol[nt]) * scale);
            }
    }
    __syncthreads();

    // coalesced write-out: thread = (row, head); 64B contiguous per part
    {
        int row = tid >> 2, head = tid & 3;
        int g = m0 + row;
        int win = g / VOL, tok = g % VOL;
        size_t off = ((size_t)(win * NHc + head) * VOL + tok) * HDc;
#pragma unroll
        for (int c = 0; c < 4; ++c)
            *(bf16x8*)(qws + off + c * 8) = *(const bf16x8*)(&Cs[row][head * 32 + c * 8]);
#pragma unroll
        for (int c = 0; c < 4; ++c)
            *(bf16x8*)(kws + off + c * 8) = *(const bf16x8*)(&Cs[row][128 + head * 32 + c * 8]);
#pragma unroll
        for (int c = 0; c < 4; ++c)
            *(bf16x8*)(vws + off + c * 8) = *(const bf16x8*)(&Cs[row][256 + head * 32 + c * 8]);
    }
}

// ---------------------------------------------------------------------------
// Kernel 2: windowed attention with online softmax. One WG per (win, head).
// Keys padded to 416 (13 k-tiles of 32); queries padded to 400 (25 q-tiles).
// ---------------------------------------------------------------------------
__global__ __launch_bounds__(256, 2)
void attn_kernel(const bf16* __restrict__ qws, const bf16* __restrict__ kws,
                 const bf16* __restrict__ vws, const bf16* __restrict__ rpb,
                 bf16* __restrict__ aows) {
    __shared__ bf16 Kl[416][40];   // row stride 80B: 2-way banks (free), 16B aligned
    __shared__ bf16 Vt[32][424];   // V transposed; stride 848B: 2-way banks
    __shared__ bf16 Pb[4][16][40]; // per-wave P tile (C/D-layout -> A-layout)
    __shared__ unsigned char clsm[416];

    const int tid = threadIdx.x;
    const int win = blockIdx.x >> 2, head = blockIdx.x & 3;
    const int wi = win & 127;
    const int wt_i = wi >> 6, wh_i = (wi >> 3) & 7, ww_i = wi & 7;

    const bf16* Qg = qws + (size_t)(win * NHc + head) * VOL * HDc;
    const bf16* Kg = kws + (size_t)(win * NHc + head) * VOL * HDc;
    const bf16* Vg = vws + (size_t)(win * NHc + head) * VOL * HDc;
    const bf16* biasg = rpb + (size_t)head * VOL * VOL;

    // stage K (zero-padded rows 392..415)
    for (int idx = tid; idx < 416 * 4; idx += 256) {
        int tok = idx >> 2, c = idx & 3;
        bf16x8 v = zero8();
        if (tok < VOL) v = *(const bf16x8*)(Kg + tok * HDc + c * 8);
        *(bf16x8*)(&Kl[tok][c * 8]) = v;
    }
    // stage V transposed (zero-padded cols)
    for (int idx = tid; idx < 416 * 4; idx += 256) {
        int tok = idx >> 2, c = idx & 3;
        bf16x8 v = zero8();
        if (tok < VOL) v = *(const bf16x8*)(Vg + tok * HDc + c * 8);
#pragma unroll
        for (int j = 0; j < 8; ++j) Vt[c * 8 + j][tok] = v[j];
    }
    // region class per token (for shift mask); 255 for pad
    for (int tok = tid; tok < 416; tok += 256) {
        unsigned char cv = 255;
        if (tok < VOL) {
            int tt = tok / 49, r2 = tok % 49, hh = r2 / 7, ww2 = r2 % 7;
            int ts = wt_i * 8 + tt, hs = wh_i * 7 + hh, ws2 = ww_i * 7 + ww2;
            int ct = (ts < 8) ? 0 : ((ts < 12) ? 1 : 2);
            int ch = (hs < 49) ? 0 : ((hs < 53) ? 1 : 2);
            int cw = (ws2 < 49) ? 0 : ((ws2 < 53) ? 1 : 2);
            cv = (unsigned char)(ct * 9 + ch * 3 + cw);
        }
        clsm[tok] = cv;
    }
    __syncthreads();

    const int wid = tid >> 6, lane = tid & 63;
    const int quad = lane >> 4, l15 = lane & 15;
    bf16* Pw = &Pb[wid][0][0];

    for (int qt = wid; qt < 25; qt += 4) {
        const int qb = qt * 16;
        int qrow = qb + l15; if (qrow >= VOL) qrow = VOL - 1;  // clamp pad rows
        bf16x8 aq = *(const bf16x8*)(Qg + (size_t)qrow * HDc + quad * 8);
        f32x4 o0 = zf4(), o1 = zf4();
        float m4[4], l4[4];
        int cq[4];
#pragma unroll
        for (int r = 0; r < 4; ++r) {
            m4[r] = -1e30f; l4[r] = 0.f;
            cq[r] = clsm[qb + quad * 4 + r];
        }

        for (int kt = 0; kt < 13; ++kt) {
            int kb = kt * 32;
            bf16x8 bk0 = *(const bf16x8*)(&Kl[kb + l15][quad * 8]);
            bf16x8 bk1 = *(const bf16x8*)(&Kl[kb + 16 + l15][quad * 8]);
            f32x4 s0 = MFMA(aq, bk0, zf4());
            f32x4 s1 = MFMA(aq, bk1, zf4());
            int ck0 = clsm[kb + l15], ck1 = clsm[kb + 16 + l15];
            int col0 = kb + l15, col1 = kb + 16 + l15;
            float t0[4], t1[4];
#pragma unroll
            for (int r = 0; r < 4; ++r) {
                int qr = qb + quad * 4 + r;
                float b0 = 0.f, b1 = 0.f;
                if (qr < VOL) {
                    const bf16* br = biasg + (size_t)qr * VOL;
                    if (col0 < VOL) b0 = (float)br[col0];
                    if (col1 < VOL) b1 = (float)br[col1];
                }
                t0[r] = s0[r] + b0 + ((cq[r] == ck0) ? 0.f : -100.f);
                t1[r] = s1[r] + b1 + ((cq[r] == ck1) ? 0.f : -100.f);
            }
            // row max over the 32 keys of this block
            float mx[4];
#pragma unroll
            for (int r = 0; r < 4; ++r) mx[r] = fmaxf(t0[r], t1[r]);
#pragma unroll
            for (int off = 8; off; off >>= 1)
#pragma unroll
                for (int r = 0; r < 4; ++r) mx[r] = fmaxf(mx[r], __shfl_xor(mx[r], off));
            float al[4], rs[4];
#pragma unroll
            for (int r = 0; r < 4; ++r) {
                float nm = fmaxf(m4[r], mx[r]);
                al[r] = __expf(m4[r] - nm);
                t0[r] = __expf(t0[r] - nm);
                t1[r] = __expf(t1[r] - nm);
                m4[r] = nm;
                rs[r] = t0[r] + t1[r];
            }
#pragma unroll
            for (int off = 8; off; off >>= 1)
#pragma unroll
                for (int r = 0; r < 4; ++r) rs[r] += __shfl_xor(rs[r], off);
#pragma unroll
            for (int r = 0; r < 4; ++r) {
                l4[r] = l4[r] * al[r] + rs[r];
                o0[r] *= al[r];
                o1[r] *= al[r];
            }
            // P: C/D layout -> LDS -> A layout (verified m120 pattern)
#pragma unroll
            for (int r = 0; r < 4; ++r) {
                int row = quad * 4 + r;
                Pw[row * 40 + l15] = (bf16)t0[r];
                Pw[row * 40 + 16 + l15] = (bf16)t1[r];
            }
            asm volatile("s_waitcnt lgkmcnt(0)" ::: "memory");  // cross-lane LDS visibility
            bf16x8 ap = *(const bf16x8*)(Pw + l15 * 40 + quad * 8);
            bf16x8 bv0 = *(const bf16x8*)(&Vt[l15][kb + quad * 8]);
            bf16x8 bv1 = *(const bf16x8*)(&Vt[16 + l15][kb + quad * 8]);
            o0 = MFMA(ap, bv0, o0);
            o1 = MFMA(ap, bv1, o1);
        }
#pragma unroll
        for (int r = 0; r < 4; ++r) {
            int qr = qb + quad * 4 + r;
            if (qr < VOL) {
                float inv = 1.f / l4[r];
                bf16* dst = aows + ((size_t)win * VOL + qr) * Cc + head * HDc;
                dst[l15] = (bf16)(o0[r] * inv);
                dst[16 + l15] = (bf16)(o1[r] * inv);
            }
        }
    }
}

// ---------------------------------------------------------------------------
// Kernel 3: output projection + window un-partition + roll-back scatter,
// fp32 output.
// ---------------------------------------------------------------------------
__global__ __launch_bounds__(256, 2)
void proj_kernel(const bf16* __restrict__ aows, const bf16* __restrict__ wp,
                 const bf16* __restrict__ bp, float* __restrict__ out) {
    __shared__ bf16 As[64][136];
    __shared__ float Csf[64][132];
    const int tid = threadIdx.x;
    const int m0 = blockIdx.x * 64;

    for (int idx = tid; idx < 64 * 16; idx += 256) {
        int r = idx >> 4, c = idx & 15;
        *(bf16x8*)(&As[r][c * 8]) = *(const bf16x8*)(aows + (size_t)(m0 + r) * Cc + c * 8);
    }
    __syncthreads();

    const int wid = tid >> 6, lane = tid & 63;
    const int quad = lane >> 4, l15 = lane & 15;

    f32x4 acc[8];
#pragma unroll
    for (int nt = 0; nt < 8; ++nt) acc[nt] = zf4();

#pragma unroll
    for (int ko = 0; ko < 4; ++ko) {
        bf16x8 af = *(const bf16x8*)(&As[wid * 16 + l15][ko * 32 + quad * 8]);
#pragma unroll
        for (int nt = 0; nt < 8; ++nt) {
            bf16x8 bfrag = *(const bf16x8*)(wp + (size_t)(nt * 16 + l15) * Cc + ko * 32 + quad * 8);
            acc[nt] = MFMA(af, bfrag, acc[nt]);
        }
    }
#pragma unroll
    for (int nt = 0; nt < 8; ++nt) {
        float bv = (float)bp[nt * 16 + l15];
#pragma unroll
        for (int r = 0; r < 4; ++r) {
            int row = wid * 16 + quad * 4 + r;
            Csf[row][nt * 16 + l15] = acc[nt][r] + bv;
        }
    }
    __syncthreads();

    // fp32 write-out with roll-back scatter: 64 rows x 32 float4-chunks
    for (int idx = tid; idx < 64 * 32; idx += 256) {
        int row = idx >> 5, ch = idx & 31;
        int g = m0 + row;
        int win = g / VOL, tok = g % VOL;
        int b = win >> 7, wi = win & 127;
        int wt_i = wi >> 6, wh_i = (wi >> 3) & 7, ww_i = wi & 7;
        int tt = tok / 49, r2 = tok % 49, hh = r2 / 7, ww2 = r2 % 7;
        int t = wt_i * 8 + tt + STc; if (t >= Tc) t -= Tc;
        int h = wh_i * 7 + hh + SHc; if (h >= Hc) h -= Hc;
        int w = ww_i * 7 + ww2 + SWc; if (w >= Wc) w -= Wc;
        float* dst = out + (size_t)(((b * Tc + t) * Hc + h) * Wc + w) * Cc + ch * 4;
        *(f32x4*)dst = *(const f32x4*)(&Csf[row][ch * 4]);
    }
}

extern "C" void kernel_launch(void* const* d_in, const int* in_sizes, int n_in,
                              void* d_out, int out_size, void* d_ws, size_t ws_size,
                              hipStream_t stream) {
    const float* x    = (const float*)d_in[0];
    const float* wqf  = (const float*)d_in[1];
    const float* bqf  = (const float*)d_in[2];
    const float* wpf  = (const float*)d_in[3];
    const float* bpf  = (const float*)d_in[4];
    const float* rpbf = (const float*)d_in[5];
    float* out = (float*)d_out;

    // ws layout (bf16 elems): converted params, then q/k/v/aows
    bf16* wqb  = (bf16*)d_ws;              // 49152
    bf16* bqb  = wqb + 49152;              // 384
    bf16* wpb  = bqb + 384;                // 16384
    bf16* bpb  = wpb + 16384;              // 128
    bf16* rpbb = bpb + 128;                // 614656
    bf16* qws  = rpbb + 614656;
    bf16* kws  = qws + QSZ;
    bf16* vws  = kws + QSZ;
    bf16* aows = vws + QSZ;                // [TWIN][VOL][C]

    hipLaunchKernelGGL(cvt_kernel, dim3((12288 + 255) / 256), dim3(256), 0, stream, wqf, wqb, 12288);
    hipLaunchKernelGGL(cvt_kernel, dim3(1), dim3(256), 0, stream, bqf, bqb, 96);
    hipLaunchKernelGGL(cvt_kernel, dim3((4096 + 255) / 256), dim3(256), 0, stream, wpf, wpb, 4096);
    hipLaunchKernelGGL(cvt_kernel, dim3(1), dim3(256), 0, stream, bpf, bpb, 32);
    hipLaunchKernelGGL(cvt_kernel, dim3((153664 + 255) / 256), dim3(256), 0, stream, rpbf, rpbb, 153664);

    hipLaunchKernelGGL(qkv_kernel, dim3(MTOT / 64), dim3(256), 0, stream,
                       x, wqb, bqb, qws, kws, vws);
    hipLaunchKernelGGL(attn_kernel, dim3(TWIN * NHc), dim3(256), 0, stream,
                       qws, kws, vws, rpbb, aows);
    hipLaunchKernelGGL(proj_kernel, dim3(MTOT / 64), dim3(256), 0, stream,
                       aows, wpb, bpb, out);
}

// Round 4
// 275.065 us; speedup vs baseline: 1.8794x; 1.8794x over previous
//
#include <hip/hip_runtime.h>
#include <hip/hip_bf16.h>

typedef __bf16 bf16;
typedef __bf16 bf16x4 __attribute__((ext_vector_type(4)));
typedef __bf16 bf16x8 __attribute__((ext_vector_type(8)));
typedef float f32x4 __attribute__((ext_vector_type(4)));

#define MFMA(a, b, c) __builtin_amdgcn_mfma_f32_16x16x32_bf16(a, b, c, 0, 0, 0)

__device__ inline f32x4 zf4() { return f32x4{0.f, 0.f, 0.f, 0.f}; }

constexpr int Bc = 2, Tc = 16, Hc = 56, Wc = 56, Cc = 128, NHc = 4, HDc = 32;
constexpr int VOL = 392;                 // 8*7*7 tokens per window
constexpr int STc = 4, SHc = 3, SWc = 3; // shift
constexpr int TWIN = 256;                // total windows (B * 128)
constexpr int MTOT = TWIN * VOL;         // 100352 tokens
constexpr int QSZ = TWIN * NHc * VOL * HDc; // elems per q/k/v ws array
constexpr int BMT_N = 8 * 4 * 400 * 416; // bias+mask table elems

__device__ inline bf16x8 zero8() {
    bf16x8 z;
#pragma unroll
    for (int j = 0; j < 8; ++j) z[j] = (bf16)0.0f;
    return z;
}

__device__ inline int cls_of(int v, int pt, int ph, int pw) {
    int tt = v / 49, rem = v % 49, hh = rem / 7, ww = rem % 7;
    int ct = pt ? (tt < 4 ? 1 : 2) : 0;
    int ch = ph ? (hh < 4 ? 1 : 2) : 0;
    int cw = pw ? (ww < 4 ? 1 : 2) : 0;
    return ct * 9 + ch * 3 + cw;
}

// ---------------------------------------------------------------------------
// Kernel 0a: fp32 -> bf16 conversion (weights / biases), x4 vec
// ---------------------------------------------------------------------------
__global__ void cvt_kernel(const float* __restrict__ src, bf16* __restrict__ dst,
                           int n4) {
    int i = blockIdx.x * blockDim.x + threadIdx.x;
    if (i < n4) {
        f32x4 v = *(const f32x4*)(src + (size_t)i * 4);
        bf16x4 o;
#pragma unroll
        for (int j = 0; j < 4; ++j) o[j] = (bf16)v[j];
        *(bf16x4*)(dst + (size_t)i * 4) = o;
    }
}

// ---------------------------------------------------------------------------
// Kernel 0b: bias+mask table: bmt[pat 8][head 4][row 400][col 416] bf16,
// value = (rpb[head][row][col] + mask(pat,row,col)) * log2(e).
// pad cols -> -144.27 (exp2 -> 0), pad rows -> 0.
// ---------------------------------------------------------------------------
__global__ void biasprep_kernel(const float* __restrict__ rpb, bf16* __restrict__ bmt) {
    int idx = blockIdx.x * 256 + threadIdx.x;
    if (idx >= BMT_N) return;
    int col = idx % 416; int t = idx / 416;
    int row = t % 400; t /= 400;
    int head = t & 3; int pat = t >> 2;
    float v;
    if (col >= VOL) v = -144.26950408889634f;
    else if (row >= VOL) v = 0.f;
    else {
        float bias = rpb[((size_t)head * VOL + row) * VOL + col];
        int pt = (pat >> 2) & 1, ph = (pat >> 1) & 1, pw = pat & 1;
        bool same = (cls_of(row, pt, ph, pw) == cls_of(col, pt, ph, pw));
        v = (bias + (same ? 0.f : -100.f)) * 1.4426950408889634f;
    }
    bmt[idx] = (bf16)v;
}

// ---------------------------------------------------------------------------
// Kernel 1: QKV projection. Gathers fp32 x rows in (shifted, window-
// partitioned) order (converting to bf16 in LDS), GEMM [64x128]@[128x384]^T
// per WG, writes q/k/v bf16 in [win][head][tok][32] layout.
// q pre-scaled by log2(e)/sqrt(32) (exp2-domain softmax).
// ---------------------------------------------------------------------------
__global__ __launch_bounds__(256, 2)
void qkv_kernel(const float* __restrict__ x, const bf16* __restrict__ wq,
                const bf16* __restrict__ bq, bf16* __restrict__ qws,
                bf16* __restrict__ kws, bf16* __restrict__ vws) {
    __shared__ bf16 As[64][136];  // 136 stride: 2-way-bank (free) for b128 reads
    __shared__ bf16 Cs[64][392];  // only cols 0..383 used
    const int tid = threadIdx.x;
    const int m0 = blockIdx.x * 64;

    // stage A: gather 64 window-token rows (roll + partition fused), cvt bf16
    for (int idx = tid; idx < 64 * 32; idx += 256) {
        int r = idx >> 5, c = idx & 31;   // c: 4-float chunk
        int g = m0 + r;
        int win = g / VOL, tok = g % VOL;
        int b = win >> 7, wi = win & 127;
        int wt_i = wi >> 6, wh_i = (wi >> 3) & 7, ww_i = wi & 7;
        int tt = tok / 49, r2 = tok % 49;
        int hh = r2 / 7, ww2 = r2 % 7;
        int t = wt_i * 8 + tt + STc; if (t >= Tc) t -= Tc;
        int h = wh_i * 7 + hh + SHc; if (h >= Hc) h -= Hc;
        int w = ww_i * 7 + ww2 + SWc; if (w >= Wc) w -= Wc;
        const float* src = x + (size_t)(((b * Tc + t) * Hc + h) * Wc + w) * Cc + c * 4;
        f32x4 v = *(const f32x4*)src;
        bf16x4 o;
#pragma unroll
        for (int j = 0; j < 4; ++j) o[j] = (bf16)v[j];
        *(bf16x4*)(&As[r][c * 4]) = o;
    }
    __syncthreads();

    const int wid = tid >> 6, lane = tid & 63;
    const int quad = lane >> 4, l15 = lane & 15;
    const int nbase = wid * 96;  // each wave: 6 n-tiles (96 cols) x 64 rows

    f32x4 acc[4][6];
#pragma unroll
    for (int ms = 0; ms < 4; ++ms)
#pragma unroll
        for (int nt = 0; nt < 6; ++nt) acc[ms][nt] = zf4();

#pragma unroll
    for (int ko = 0; ko < 4; ++ko) {
        bf16x8 af[4];
#pragma unroll
        for (int ms = 0; ms < 4; ++ms)
            af[ms] = *(const bf16x8*)(&As[ms * 16 + l15][ko * 32 + quad * 8]);
#pragma unroll
        for (int nt = 0; nt < 6; ++nt) {
            int n = nbase + nt * 16 + l15;
            bf16x8 bfrag = *(const bf16x8*)(wq + (size_t)n * Cc + ko * 32 + quad * 8);
#pragma unroll
            for (int ms = 0; ms < 4; ++ms)
                acc[ms][nt] = MFMA(af[ms], bfrag, acc[ms][nt]);
        }
    }

    float bcol[6];
#pragma unroll
    for (int nt = 0; nt < 6; ++nt) bcol[nt] = (float)bq[nbase + nt * 16 + l15];

#pragma unroll
    for (int nt = 0; nt < 6; ++nt) {
        int col = nbase + nt * 16 + l15;
        // q: log2(e)/sqrt(32) so softmax exp uses raw v_exp_f32 (exp2)
        float scale = (col < 128) ? 0.25505653942f : 1.0f;
#pragma unroll
        for (int ms = 0; ms < 4; ++ms)
#pragma unroll
            for (int r = 0; r < 4; ++r) {
                int row = ms * 16 + quad * 4 + r;
                Cs[row][col] = (bf16)((acc[ms][nt][r] + bcol[nt]) * scale);
            }
    }
    __syncthreads();

    // coalesced write-out: thread = (row, head); 64B contiguous per part
    {
        int row = tid >> 2, head = tid & 3;
        int g = m0 + row;
        int win = g / VOL, tok = g % VOL;
        size_t off = ((size_t)(win * NHc + head) * VOL + tok) * HDc;
#pragma unroll
        for (int c = 0; c < 4; ++c)
            *(bf16x8*)(qws + off + c * 8) = *(const bf16x8*)(&Cs[row][head * 32 + c * 8]);
#pragma unroll
        for (int c = 0; c < 4; ++c)
            *(bf16x8*)(kws + off + c * 8) = *(const bf16x8*)(&Cs[row][128 + head * 32 + c * 8]);
#pragma unroll
        for (int c = 0; c < 4; ++c)
            *(bf16x8*)(vws + off + c * 8) = *(const bf16x8*)(&Cs[row][256 + head * 32 + c * 8]);
    }
}

// ---------------------------------------------------------------------------
// Kernel 2: windowed attention, S^T formulation, no online softmax.
// One WG (512 thr, 8 waves) per (win, head). Keys padded to 416.
//   S^T = MFMA(K_frag, Q_frag, biasmask)   -> lane holds 4 consecutive toks
//   P = exp2(S^T) -> 2x ds_write_b64 -> read as B-frag (b128)
//   O^T = MFMA(V^T_frag, P_frag)           -> vectorized bf16x4 stores
// Row-sum: per-lane accumulate + 2 shuffles (quad reduce) per q-tile.
// ---------------------------------------------------------------------------
__global__ __launch_bounds__(512, 4)
void attn_kernel(const bf16* __restrict__ qws, const bf16* __restrict__ kws,
                 const bf16* __restrict__ vws, const bf16* __restrict__ bmt,
                 bf16* __restrict__ aows) {
    __shared__ bf16 Kl[416][40];   // row stride 80B: 2-way banks (free)
    __shared__ bf16 Vt[32][424];   // V transposed
    __shared__ bf16 Pb[8][16][40]; // per-wave P tile (row-major P, tok-contig)

    const int tid = threadIdx.x;
    const int win = blockIdx.x >> 2, head = blockIdx.x & 3;
    const int wi = win & 127;
    const int wt_i = wi >> 6, wh_i = (wi >> 3) & 7, ww_i = wi & 7;
    const int pat = ((wt_i == 1) << 2) | ((wh_i == 7) << 1) | (ww_i == 7);

    const bf16* Qg = qws + (size_t)(win * NHc + head) * VOL * HDc;
    const bf16* Kg = kws + (size_t)(win * NHc + head) * VOL * HDc;
    const bf16* Vg = vws + (size_t)(win * NHc + head) * VOL * HDc;
    const bf16* Bg = bmt + (size_t)(pat * NHc + head) * 400 * 416;

    // stage K (zero-padded rows 392..415)
    for (int idx = tid; idx < 416 * 4; idx += 512) {
        int tok = idx >> 2, c = idx & 3;
        bf16x8 v = zero8();
        if (tok < VOL) v = *(const bf16x8*)(Kg + tok * HDc + c * 8);
        *(bf16x8*)(&Kl[tok][c * 8]) = v;
    }
    // stage V transposed (zero-padded cols)
    for (int idx = tid; idx < 416 * 4; idx += 512) {
        int tok = idx >> 2, c = idx & 3;
        bf16x8 v = zero8();
        if (tok < VOL) v = *(const bf16x8*)(Vg + tok * HDc + c * 8);
#pragma unroll
        for (int j = 0; j < 8; ++j) Vt[c * 8 + j][tok] = v[j];
    }
    __syncthreads();

    const int wid = tid >> 6, lane = tid & 63;
    const int quad = lane >> 4, l15 = lane & 15;
    bf16* Pw = &Pb[wid][0][0];

    for (int qt = wid; qt < 25; qt += 8) {
        const int qb = qt * 16;
        const int qrow = (qb + l15 < VOL) ? (qb + l15) : (VOL - 1);
        const bf16x8 qf = *(const bf16x8*)(Qg + (size_t)qrow * HDc + quad * 8);
        const bf16* Brow = Bg + (size_t)(qb + l15) * 416;
        f32x4 o0 = zf4(), o1 = zf4();
        float lsum = 0.f;
        // software-prefetch bias C-frags one kt ahead
        bf16x4 nb0 = *(const bf16x4*)(Brow + quad * 4);
        bf16x4 nb1 = *(const bf16x4*)(Brow + 16 + quad * 4);
#pragma unroll 1
        for (int kt = 0; kt < 13; ++kt) {
            const int kb = kt * 32;
            f32x4 c0, c1;
#pragma unroll
            for (int j = 0; j < 4; ++j) { c0[j] = (float)nb0[j]; c1[j] = (float)nb1[j]; }
            bf16x8 kf0 = *(const bf16x8*)(&Kl[kb + l15][quad * 8]);
            bf16x8 kf1 = *(const bf16x8*)(&Kl[kb + 16 + l15][quad * 8]);
            if (kt < 12) {
                nb0 = *(const bf16x4*)(Brow + kb + 32 + quad * 4);
                nb1 = *(const bf16x4*)(Brow + kb + 48 + quad * 4);
            }
            // S^T tiles: rows = toks (kb+quad*4+r | +16), col = qrow (l15)
            f32x4 s0 = MFMA(kf0, qf, c0);
            f32x4 s1 = MFMA(kf1, qf, c1);
            bf16x4 p0, p1;
            float ls = 0.f;
#pragma unroll
            for (int r = 0; r < 4; ++r) {
                float e0 = __builtin_amdgcn_exp2f(s0[r]);
                float e1 = __builtin_amdgcn_exp2f(s1[r]);
                p0[r] = (bf16)e0; p1[r] = (bf16)e1;
                ls += e0 + e1;
            }
            lsum += ls;
            // P row-major [qrow_local][tok_local]: tok-contiguous b64 writes
            *(bf16x4*)(Pw + l15 * 40 + quad * 4) = p0;
            *(bf16x4*)(Pw + l15 * 40 + 16 + quad * 4) = p1;
            asm volatile("s_waitcnt lgkmcnt(0)" ::: "memory");
            bf16x8 pf = *(const bf16x8*)(Pw + l15 * 40 + quad * 8);
            bf16x8 vf0 = *(const bf16x8*)(&Vt[l15][kb + quad * 8]);
            bf16x8 vf1 = *(const bf16x8*)(&Vt[16 + l15][kb + quad * 8]);
            // O^T[hd][qrow]
            o0 = MFMA(vf0, pf, o0);
            o1 = MFMA(vf1, pf, o1);
        }
        lsum += __shfl_xor(lsum, 16);
        lsum += __shfl_xor(lsum, 32);
        if (qb + l15 < VOL) {
            float inv = 1.f / lsum;
            bf16x4 w0, w1;
#pragma unroll
            for (int r = 0; r < 4; ++r) {
                w0[r] = (bf16)(o0[r] * inv);
                w1[r] = (bf16)(o1[r] * inv);
            }
            bf16* dst = aows + ((size_t)win * VOL + qb + l15) * Cc + head * HDc;
            *(bf16x4*)(dst + quad * 4) = w0;
            *(bf16x4*)(dst + 16 + quad * 4) = w1;
        }
    }
}

// ---------------------------------------------------------------------------
// Kernel 3: output projection + window un-partition + roll-back scatter,
// fp32 output.
// ---------------------------------------------------------------------------
__global__ __launch_bounds__(256, 2)
void proj_kernel(const bf16* __restrict__ aows, const bf16* __restrict__ wp,
                 const bf16* __restrict__ bp, float* __restrict__ out) {
    __shared__ bf16 As[64][136];
    __shared__ float Csf[64][132];
    const int tid = threadIdx.x;
    const int m0 = blockIdx.x * 64;

    for (int idx = tid; idx < 64 * 16; idx += 256) {
        int r = idx >> 4, c = idx & 15;
        *(bf16x8*)(&As[r][c * 8]) = *(const bf16x8*)(aows + (size_t)(m0 + r) * Cc + c * 8);
    }
    __syncthreads();

    const int wid = tid >> 6, lane = tid & 63;
    const int quad = lane >> 4, l15 = lane & 15;

    f32x4 acc[8];
#pragma unroll
    for (int nt = 0; nt < 8; ++nt) acc[nt] = zf4();

#pragma unroll
    for (int ko = 0; ko < 4; ++ko) {
        bf16x8 af = *(const bf16x8*)(&As[wid * 16 + l15][ko * 32 + quad * 8]);
#pragma unroll
        for (int nt = 0; nt < 8; ++nt) {
            bf16x8 bfrag = *(const bf16x8*)(wp + (size_t)(nt * 16 + l15) * Cc + ko * 32 + quad * 8);
            acc[nt] = MFMA(af, bfrag, acc[nt]);
        }
    }
#pragma unroll
    for (int nt = 0; nt < 8; ++nt) {
        float bv = (float)bp[nt * 16 + l15];
#pragma unroll
        for (int r = 0; r < 4; ++r) {
            int row = wid * 16 + quad * 4 + r;
            Csf[row][nt * 16 + l15] = acc[nt][r] + bv;
        }
    }
    __syncthreads();

    // fp32 write-out with roll-back scatter: 64 rows x 32 float4-chunks
    for (int idx = tid; idx < 64 * 32; idx += 256) {
        int row = idx >> 5, ch = idx & 31;
        int g = m0 + row;
        int win = g / VOL, tok = g % VOL;
        int b = win >> 7, wi = win & 127;
        int wt_i = wi >> 6, wh_i = (wi >> 3) & 7, ww_i = wi & 7;
        int tt = tok / 49, r2 = tok % 49, hh = r2 / 7, ww2 = r2 % 7;
        int t = wt_i * 8 + tt + STc; if (t >= Tc) t -= Tc;
        int h = wh_i * 7 + hh + SHc; if (h >= Hc) h -= Hc;
        int w = ww_i * 7 + ww2 + SWc; if (w >= Wc) w -= Wc;
        float* dst = out + (size_t)(((b * Tc + t) * Hc + h) * Wc + w) * Cc + ch * 4;
        *(f32x4*)dst = *(const f32x4*)(&Csf[row][ch * 4]);
    }
}

extern "C" void kernel_launch(void* const* d_in, const int* in_sizes, int n_in,
                              void* d_out, int out_size, void* d_ws, size_t ws_size,
                              hipStream_t stream) {
    const float* x    = (const float*)d_in[0];
    const float* wqf  = (const float*)d_in[1];
    const float* bqf  = (const float*)d_in[2];
    const float* wpf  = (const float*)d_in[3];
    const float* bpf  = (const float*)d_in[4];
    const float* rpbf = (const float*)d_in[5];
    float* out = (float*)d_out;

    // ws layout (bf16 elems): converted params, bias+mask table, q/k/v/aows
    bf16* wqb  = (bf16*)d_ws;              // 49152
    bf16* bqb  = wqb + 49152;              // 384
    bf16* wpb  = bqb + 384;                // 16384
    bf16* bpb  = wpb + 16384;              // 128
    bf16* bmt  = bpb + 128;                // 5324800
    bf16* qws  = bmt + BMT_N;
    bf16* kws  = qws + QSZ;
    bf16* vws  = kws + QSZ;
    bf16* aows = vws + QSZ;                // [TWIN][VOL][C]

    hipLaunchKernelGGL(cvt_kernel, dim3((12288 + 255) / 256), dim3(256), 0, stream, wqf, wqb, 12288);
    hipLaunchKernelGGL(cvt_kernel, dim3(1), dim3(256), 0, stream, bqf, bqb, 96);
    hipLaunchKernelGGL(cvt_kernel, dim3((4096 + 255) / 256), dim3(256), 0, stream, wpf, wpb, 4096);
    hipLaunchKernelGGL(cvt_kernel, dim3(1), dim3(256), 0, stream, bpf, bpb, 32);
    hipLaunchKernelGGL(biasprep_kernel, dim3((BMT_N + 255) / 256), dim3(256), 0, stream, rpbf, bmt);

    hipLaunchKernelGGL(qkv_kernel, dim3(MTOT / 64), dim3(256), 0, stream,
                       x, wqb, bqb, qws, kws, vws);
    hipLaunchKernelGGL(attn_kernel, dim3(TWIN * NHc), dim3(512), 0, stream,
                       qws, kws, vws, bmt, aows);
    hipLaunchKernelGGL(proj_kernel, dim3(MTOT / 64), dim3(256), 0, stream,
                       aows, wpb, bpb, out);
}

// Round 5
// 273.210 us; speedup vs baseline: 1.8921x; 1.0068x over previous
//
#include <hip/hip_runtime.h>
#include <hip/hip_bf16.h>

typedef __bf16 bf16;
typedef __bf16 bf16x4 __attribute__((ext_vector_type(4)));
typedef __bf16 bf16x8 __attribute__((ext_vector_type(8)));
typedef float f32x4 __attribute__((ext_vector_type(4)));

#define MFMA(a, b, c) __builtin_amdgcn_mfma_f32_16x16x32_bf16(a, b, c, 0, 0, 0)

__device__ inline f32x4 zf4() { return f32x4{0.f, 0.f, 0.f, 0.f}; }

constexpr int Tc = 16, Hc = 56, Wc = 56, Cc = 128, NHc = 4, HDc = 32;
constexpr int VOL = 392;                 // 8*7*7 tokens per window
constexpr int STc = 4, SHc = 3, SWc = 3; // shift
constexpr int TWIN = 256;                // total windows (B * 128)
constexpr int MTOT = TWIN * VOL;         // 100352 tokens
constexpr int QSZ = TWIN * NHc * VOL * HDc;
constexpr int BMT_N = 4 * 400 * 416;     // bias table elems (per-head, no pattern dup)
constexpr int OH_N = 8 * 416 * 32;       // onehot table elems per side

__device__ inline bf16x8 zero8() {
    bf16x8 z;
#pragma unroll
    for (int j = 0; j < 8; ++j) z[j] = (bf16)0.0f;
    return z;
}

__device__ inline f32x4 up4(bf16x4 b) {
    f32x4 r;
#pragma unroll
    for (int j = 0; j < 4; ++j) r[j] = (float)b[j];
    return r;
}

__device__ inline int cls_of(int v, int pt, int ph, int pw) {
    int tt = v / 49, rem = v % 49, hh = rem / 7, ww = rem % 7;
    int ct = pt ? (tt < 4 ? 1 : 2) : 0;
    int ch = ph ? (hh < 4 ? 1 : 2) : 0;
    int cw = pw ? (ww < 4 ? 1 : 2) : 0;
    return ct * 9 + ch * 3 + cw;
}

// ---------------------------------------------------------------------------
// Kernel 0a: fp32 -> bf16 for all 4 params in one launch.
// ---------------------------------------------------------------------------
__global__ void cvt_params(const float* __restrict__ wq, const float* __restrict__ bq,
                           const float* __restrict__ wp, const float* __restrict__ bp,
                           bf16* __restrict__ wqb, bf16* __restrict__ bqb,
                           bf16* __restrict__ wpb, bf16* __restrict__ bpb) {
    int i = blockIdx.x * 256 + threadIdx.x;
    const float* s; bf16* d; int off;
    if (i < 12288)       { s = wq; d = wqb; off = i; }
    else if (i < 12384)  { s = bq; d = bqb; off = i - 12288; }
    else if (i < 16480)  { s = wp; d = wpb; off = i - 12384; }
    else if (i < 16512)  { s = bp; d = bpb; off = i - 16480; }
    else return;
    f32x4 v = *(const f32x4*)(s + (size_t)off * 4);
    bf16x4 o;
#pragma unroll
    for (int j = 0; j < 4; ++j) o[j] = (bf16)v[j];
    *(bf16x4*)(d + (size_t)off * 4) = o;
}

// ---------------------------------------------------------------------------
// Kernel 0b: bias table bmt[head 4][row 400][col 416] bf16 = rpb * log2e.
// pad rows -> 0, pad cols -> -144 (exp2 -> ~0).
// ---------------------------------------------------------------------------
__global__ void biasprep_kernel(const float* __restrict__ rpb, bf16* __restrict__ bmt) {
    int i = blockIdx.x * 256 + threadIdx.x;
    if (i >= 4 * 400 * 104) return;
    int c4 = i % 104; int t = i / 104;
    int row = t % 400; int head = t / 400;
    f32x4 v;
    if (row >= VOL) {
#pragma unroll
        for (int j = 0; j < 4; ++j) v[j] = 0.f;
    } else if (c4 >= 98) {
#pragma unroll
        for (int j = 0; j < 4; ++j) v[j] = -144.0f;
    } else {
        f32x4 b = *(const f32x4*)(rpb + ((size_t)(head * VOL + row) * VOL + c4 * 4));
#pragma unroll
        for (int j = 0; j < 4; ++j) v[j] = b[j] * 1.4426950408889634f;
    }
    bf16x4 o;
#pragma unroll
    for (int j = 0; j < 4; ++j) o[j] = (bf16)v[j];
    *(bf16x4*)(bmt + ((size_t)(head * 400) * 416 + (size_t)(t % 400) * 416 - (size_t)(t % 400) * 416) + (size_t)t * 416 + c4 * 4) = o;
}

// ---------------------------------------------------------------------------
// Kernel 0c: onehot class tables for mask-as-MFMA.
//   ohq[pat][tok][ch]: ch==cls -> 12, ch31 -> +12  (pad tok: only ch31)
//   ohk[pat][tok][ch]: ch==cls -> 12, ch31 -> -12  (pad tok: only ch31)
//   ind-MFMA = 144*samecls - 144: 0 for valid pairs, -144 for masked/pad.
// ---------------------------------------------------------------------------
__global__ void ohprep_kernel(bf16* __restrict__ ohq, bf16* __restrict__ ohk) {
    int i = blockIdx.x * 256 + threadIdx.x;
    if (i >= 8 * 416) return;
    int tok = i % 416, pat = i / 416;
    int pt = (pat >> 2) & 1, ph = (pat >> 1) & 1, pw = pat & 1;
    int cls = (tok < VOL) ? cls_of(tok, pt, ph, pw) : -1;
    bf16* dq = ohq + (size_t)i * 32;
    bf16* dk = ohk + (size_t)i * 32;
    for (int ch = 0; ch < 32; ++ch) {
        float qv = (ch == cls) ? 12.0f : ((ch == 31) ? 12.0f : 0.f);
        float kv = (ch == cls) ? 12.0f : ((ch == 31) ? -12.0f : 0.f);
        dq[ch] = (bf16)qv;
        dk[ch] = (bf16)kv;
    }
}

// ---------------------------------------------------------------------------
// Kernel 1: QKV projection (roll+partition fused gather, bf16 MFMA GEMM).
// q pre-scaled by log2(e)/sqrt(32).
// ---------------------------------------------------------------------------
__global__ __launch_bounds__(256, 2)
void qkv_kernel(const float* __restrict__ x, const bf16* __restrict__ wq,
                const bf16* __restrict__ bq, bf16* __restrict__ qws,
                bf16* __restrict__ kws, bf16* __restrict__ vws) {
    __shared__ bf16 As[64][136];
    __shared__ bf16 Cs[64][396];   // stride 396: conflict-free epilogue writes
    __shared__ unsigned int rb[64];   // x byte offsets per row
    __shared__ unsigned int rbw[64];  // packed (win<<9)|tok per row
    const int tid = threadIdx.x;
    const int m0 = blockIdx.x * 64;

    if (tid < 64) {
        int g = m0 + tid;
        int win = g / VOL, tok = g % VOL;
        int b = win >> 7, wi = win & 127;
        int wt_i = wi >> 6, wh_i = (wi >> 3) & 7, ww_i = wi & 7;
        int tt = tok / 49, r2 = tok % 49, hh = r2 / 7, ww2 = r2 % 7;
        int t = wt_i * 8 + tt + STc; if (t >= Tc) t -= Tc;
        int h = wh_i * 7 + hh + SHc; if (h >= Hc) h -= Hc;
        int w = ww_i * 7 + ww2 + SWc; if (w >= Wc) w -= Wc;
        rb[tid] = (unsigned int)((((b * Tc + t) * Hc + h) * Wc + w) * Cc * 4);
        rbw[tid] = (unsigned int)((win << 9) | tok);
    }
    __syncthreads();

    for (int idx = tid; idx < 64 * 32; idx += 256) {
        int r = idx >> 5, c = idx & 31;
        const float* src = (const float*)((const char*)x + rb[r]) + c * 4;
        f32x4 v = *(const f32x4*)src;
        bf16x4 o;
#pragma unroll
        for (int j = 0; j < 4; ++j) o[j] = (bf16)v[j];
        *(bf16x4*)(&As[r][c * 4]) = o;
    }
    __syncthreads();

    const int wid = tid >> 6, lane = tid & 63;
    const int quad = lane >> 4, l15 = lane & 15;
    const int nbase = wid * 96;

    f32x4 acc[4][6];
#pragma unroll
    for (int ms = 0; ms < 4; ++ms)
#pragma unroll
        for (int nt = 0; nt < 6; ++nt) acc[ms][nt] = zf4();

#pragma unroll
    for (int ko = 0; ko < 4; ++ko) {
        bf16x8 af[4];
#pragma unroll
        for (int ms = 0; ms < 4; ++ms)
            af[ms] = *(const bf16x8*)(&As[ms * 16 + l15][ko * 32 + quad * 8]);
#pragma unroll
        for (int nt = 0; nt < 6; ++nt) {
            int n = nbase + nt * 16 + l15;
            bf16x8 bfrag = *(const bf16x8*)(wq + (size_t)n * Cc + ko * 32 + quad * 8);
#pragma unroll
            for (int ms = 0; ms < 4; ++ms)
                acc[ms][nt] = MFMA(af[ms], bfrag, acc[ms][nt]);
        }
    }

    float bcol[6];
#pragma unroll
    for (int nt = 0; nt < 6; ++nt) bcol[nt] = (float)bq[nbase + nt * 16 + l15];

#pragma unroll
    for (int nt = 0; nt < 6; ++nt) {
        int col = nbase + nt * 16 + l15;
        float scale = (col < 128) ? 0.25505653942f : 1.0f;  // log2e/sqrt(32) on q
#pragma unroll
        for (int ms = 0; ms < 4; ++ms)
#pragma unroll
            for (int r = 0; r < 4; ++r) {
                int row = ms * 16 + quad * 4 + r;
                Cs[row][col] = (bf16)((acc[ms][nt][r] + bcol[nt]) * scale);
            }
    }
    __syncthreads();

    {
        int row = tid >> 2, hh4 = tid & 3;
        unsigned int p = rbw[row];
        int win = p >> 9, tok = p & 511;
        size_t off = ((size_t)(win * NHc + hh4) * VOL + tok) * HDc;
#pragma unroll
        for (int c = 0; c < 4; ++c) {
            bf16x4 lo = *(const bf16x4*)(&Cs[row][hh4 * 32 + c * 8]);
            bf16x4 hi = *(const bf16x4*)(&Cs[row][hh4 * 32 + c * 8 + 4]);
            *(bf16x8*)(qws + off + c * 8) = __builtin_shufflevector(lo, hi, 0, 1, 2, 3, 4, 5, 6, 7);
        }
#pragma unroll
        for (int c = 0; c < 4; ++c) {
            bf16x4 lo = *(const bf16x4*)(&Cs[row][128 + hh4 * 32 + c * 8]);
            bf16x4 hi = *(const bf16x4*)(&Cs[row][128 + hh4 * 32 + c * 8 + 4]);
            *(bf16x8*)(kws + off + c * 8) = __builtin_shufflevector(lo, hi, 0, 1, 2, 3, 4, 5, 6, 7);
        }
#pragma unroll
        for (int c = 0; c < 4; ++c) {
            bf16x4 lo = *(const bf16x4*)(&Cs[row][256 + hh4 * 32 + c * 8]);
            bf16x4 hi = *(const bf16x4*)(&Cs[row][256 + hh4 * 32 + c * 8 + 4]);
            *(bf16x8*)(vws + off + c * 8) = __builtin_shufflevector(lo, hi, 0, 1, 2, 3, 4, 5, 6, 7);
        }
    }
}

// ---------------------------------------------------------------------------
// Kernel 2: windowed attention, S^T formulation, mask-as-MFMA, PV pipelined.
// 512 thr/WG, one WG per (win,head). 2 q-tiles per wave for ILP.
// ---------------------------------------------------------------------------
__global__ __launch_bounds__(512, 4)
void attn_kernel(const bf16* __restrict__ qws, const bf16* __restrict__ kws,
                 const bf16* __restrict__ vws, const bf16* __restrict__ bmt,
                 const bf16* __restrict__ ohqt, const bf16* __restrict__ ohkt,
                 bf16* __restrict__ aows) {
    __shared__ bf16 Kl[400][40];      // rows 392..399 zero (kt12 is half-tile)
    __shared__ bf16 Vt[32][424];      // V transposed
    __shared__ bf16 Pb[8][2][16][40]; // per-wave, per-tile P

    const int tid = threadIdx.x;
    const int win = blockIdx.x >> 2, head = blockIdx.x & 3;
    const int wi = win & 127;
    const int wt_i = wi >> 6, wh_i = (wi >> 3) & 7, ww_i = wi & 7;
    const int pat = ((wt_i == 1) << 2) | ((wh_i == 7) << 1) | (ww_i == 7);
    const bool masked = (pat != 0);

    const bf16* Qg = qws + (size_t)(win * NHc + head) * VOL * HDc;
    const bf16* Kg = kws + (size_t)(win * NHc + head) * VOL * HDc;
    const bf16* Vg = vws + (size_t)(win * NHc + head) * VOL * HDc;
    const bf16* Bg = bmt + (size_t)head * 400 * 416;
    const bf16* ohq_p = ohqt + (size_t)pat * 416 * 32;
    const bf16* ohk_p = ohkt + (size_t)pat * 416 * 32;

    for (int idx = tid; idx < 400 * 4; idx += 512) {
        int tok = idx >> 2, c = idx & 3;
        bf16x8 v = zero8();
        if (tok < VOL) v = *(const bf16x8*)(Kg + tok * HDc + c * 8);
        *(bf16x8*)(&Kl[tok][c * 8]) = v;
    }
    if (tid < 416) {  // V transpose: b64 chunks of 4 toks
        int c = tid & 3, tok4 = (tid >> 2) * 4;
        bf16x8 rr[4];
#pragma unroll
        for (int i = 0; i < 4; ++i)
            rr[i] = (tok4 + i < VOL) ? *(const bf16x8*)(Vg + (tok4 + i) * HDc + c * 8) : zero8();
#pragma unroll
        for (int j = 0; j < 8; ++j) {
            bf16x4 wv;
            wv[0] = rr[0][j]; wv[1] = rr[1][j]; wv[2] = rr[2][j]; wv[3] = rr[3][j];
            *(bf16x4*)(&Vt[c * 8 + j][tok4]) = wv;
        }
    }
    __syncthreads();

    const int wid = tid >> 6, lane = tid & 63;
    const int quad = lane >> 4, l15 = lane & 15;
    bf16* PwA = &Pb[wid][0][0][0];
    bf16* PwB = &Pb[wid][1][0][0];

    for (int pass = 0; pass < 2; ++pass) {
        const int qtA = pass * 16 + wid, qtB = qtA + 8;
        const bool hasB = (qtB < 25);
        const int qbA = qtA * 16, qbB = qtB * 16;
        int qrA = qbA + l15; if (qrA >= VOL) qrA = VOL - 1;
        const bf16x8 qfA = *(const bf16x8*)(Qg + (size_t)qrA * HDc + quad * 8);
        const bf16* BrA = Bg + (size_t)(qbA + l15) * 416;
        const bf16* BrB = BrA;
        bf16x8 qfB, ohqA, ohqB;
        if (masked) ohqA = *(const bf16x8*)(ohq_p + (size_t)(qbA + l15) * 32 + quad * 8);
        if (hasB) {
            int qrB = qbB + l15; if (qrB >= VOL) qrB = VOL - 1;
            qfB = *(const bf16x8*)(Qg + (size_t)qrB * HDc + quad * 8);
            BrB = Bg + (size_t)(qbB + l15) * 416;
            if (masked) ohqB = *(const bf16x8*)(ohq_p + (size_t)(qbB + l15) * 32 + quad * 8);
        }
        f32x4 oA0 = zf4(), oA1 = zf4(), oB0 = zf4(), oB1 = zf4();
        float lsA = 0.f, lsB = 0.f;
        bf16x4 nbA0 = *(const bf16x4*)(BrA);
        bf16x4 nbA1 = *(const bf16x4*)(BrA + 16);
        bf16x4 nbB0, nbB1;
        if (hasB) { nbB0 = *(const bf16x4*)(BrB); nbB1 = *(const bf16x4*)(BrB + 16); }

        auto qk_full = [&](int kb) {
            bf16x8 kf0 = *(const bf16x8*)(&Kl[kb + l15][quad * 8]);
            bf16x8 kf1 = *(const bf16x8*)(&Kl[kb + 16 + l15][quad * 8]);
            bf16x8 ok0, ok1;
            if (masked) {
                ok0 = *(const bf16x8*)(ohk_p + (size_t)(kb + l15) * 32 + quad * 8);
                ok1 = *(const bf16x8*)(ohk_p + (size_t)(kb + 16 + l15) * 32 + quad * 8);
            }
            f32x4 cA0 = up4(nbA0), cA1 = up4(nbA1), cB0, cB1;
            if (hasB) { cB0 = up4(nbB0); cB1 = up4(nbB1); }
            if (kb < 384) {
                nbA0 = *(const bf16x4*)(BrA + kb + 32);
                nbA1 = *(const bf16x4*)(BrA + kb + 48);
                if (hasB) {
                    nbB0 = *(const bf16x4*)(BrB + kb + 32);
                    nbB1 = *(const bf16x4*)(BrB + kb + 48);
                }
            }
            if (masked) {
                cA0 = MFMA(ok0, ohqA, cA0);
                cA1 = MFMA(ok1, ohqA, cA1);
                if (hasB) { cB0 = MFMA(ok0, ohqB, cB0); cB1 = MFMA(ok1, ohqB, cB1); }
            }
            f32x4 sA0 = MFMA(kf0, qfA, cA0);
            f32x4 sA1 = MFMA(kf1, qfA, cA1);
            bf16x4 pA0, pA1;
            float la = 0.f;
#pragma unroll
            for (int r = 0; r < 4; ++r) {
                float e0 = __builtin_amdgcn_exp2f(sA0[r]);
                float e1 = __builtin_amdgcn_exp2f(sA1[r]);
                pA0[r] = (bf16)e0; pA1[r] = (bf16)e1; la += e0 + e1;
            }
            lsA += la;
            *(bf16x4*)(PwA + l15 * 40 + quad * 4) = pA0;
            *(bf16x4*)(PwA + l15 * 40 + 16 + quad * 4) = pA1;
            if (hasB) {
                f32x4 sB0 = MFMA(kf0, qfB, cB0);
                f32x4 sB1 = MFMA(kf1, qfB, cB1);
                bf16x4 pB0, pB1;
                float lb = 0.f;
#pragma unroll
                for (int r = 0; r < 4; ++r) {
                    float e0 = __builtin_amdgcn_exp2f(sB0[r]);
                    float e1 = __builtin_amdgcn_exp2f(sB1[r]);
                    pB0[r] = (bf16)e0; pB1[r] = (bf16)e1; lb += e0 + e1;
                }
                lsB += lb;
                *(bf16x4*)(PwB + l15 * 40 + quad * 4) = pB0;
                *(bf16x4*)(PwB + l15 * 40 + 16 + quad * 4) = pB1;
            }
        };
        auto pv = [&](int kb) {
            bf16x8 pfA = *(const bf16x8*)(PwA + l15 * 40 + quad * 8);
            bf16x8 pfB;
            if (hasB) pfB = *(const bf16x8*)(PwB + l15 * 40 + quad * 8);
            bf16x8 vf0 = *(const bf16x8*)(&Vt[l15][kb + quad * 8]);
            bf16x8 vf1 = *(const bf16x8*)(&Vt[16 + l15][kb + quad * 8]);
            oA0 = MFMA(vf0, pfA, oA0);
            oA1 = MFMA(vf1, pfA, oA1);
            if (hasB) { oB0 = MFMA(vf0, pfB, oB0); oB1 = MFMA(vf1, pfB, oB1); }
        };

        qk_full(0);
#pragma unroll 1
        for (int kt = 1; kt < 12; ++kt) {
            pv((kt - 1) * 32);   // reads P(kt-1) BEFORE P(kt) writes: WAR-safe (DS in-order)
            qk_full(kt * 32);
        }
        pv(352);
        {   // kt = 12: only first 16-token half is (partially) real
            bf16x8 kf0 = *(const bf16x8*)(&Kl[384 + l15][quad * 8]);
            bf16x8 ok0;
            if (masked) ok0 = *(const bf16x8*)(ohk_p + (size_t)(384 + l15) * 32 + quad * 8);
            f32x4 cA0 = up4(nbA0), cB0;
            if (hasB) cB0 = up4(nbB0);
            if (masked) {
                cA0 = MFMA(ok0, ohqA, cA0);
                if (hasB) cB0 = MFMA(ok0, ohqB, cB0);
            }
            f32x4 sA0 = MFMA(kf0, qfA, cA0);
            bf16x4 pA0, z4;
            float la = 0.f;
#pragma unroll
            for (int r = 0; r < 4; ++r) {
                float e0 = __builtin_amdgcn_exp2f(sA0[r]);
                pA0[r] = (bf16)e0; la += e0; z4[r] = (bf16)0.f;
            }
            lsA += la;
            *(bf16x4*)(PwA + l15 * 40 + quad * 4) = pA0;
            *(bf16x4*)(PwA + l15 * 40 + 16 + quad * 4) = z4;
            if (hasB) {
                f32x4 sB0 = MFMA(kf0, qfB, cB0);
                bf16x4 pB0;
                float lb = 0.f;
#pragma unroll
                for (int r = 0; r < 4; ++r) {
                    float e0 = __builtin_amdgcn_exp2f(sB0[r]);
                    pB0[r] = (bf16)e0; lb += e0;
                }
                lsB += lb;
                *(bf16x4*)(PwB + l15 * 40 + quad * 4) = pB0;
                *(bf16x4*)(PwB + l15 * 40 + 16 + quad * 4) = z4;
            }
        }
        pv(384);

        lsA += __shfl_xor(lsA, 16); lsA += __shfl_xor(lsA, 32);
        if (hasB) { lsB += __shfl_xor(lsB, 16); lsB += __shfl_xor(lsB, 32); }
        if (qbA + l15 < VOL) {
            float inv = 1.f / lsA;
            bf16x4 w0, w1;
#pragma unroll
            for (int r = 0; r < 4; ++r) { w0[r] = (bf16)(oA0[r] * inv); w1[r] = (bf16)(oA1[r] * inv); }
            bf16* dst = aows + ((size_t)win * VOL + qbA + l15) * Cc + head * HDc;
            *(bf16x4*)(dst + quad * 4) = w0;
            *(bf16x4*)(dst + 16 + quad * 4) = w1;
        }
        if (hasB && qbB + l15 < VOL) {
            float inv = 1.f / lsB;
            bf16x4 w0, w1;
#pragma unroll
            for (int r = 0; r < 4; ++r) { w0[r] = (bf16)(oB0[r] * inv); w1[r] = (bf16)(oB1[r] * inv); }
            bf16* dst = aows + ((size_t)win * VOL + qbB + l15) * Cc + head * HDc;
            *(bf16x4*)(dst + quad * 4) = w0;
            *(bf16x4*)(dst + 16 + quad * 4) = w1;
        }
    }
}

// ---------------------------------------------------------------------------
// Kernel 3: output projection + un-partition + roll-back scatter, fp32 out.
// ---------------------------------------------------------------------------
__global__ __launch_bounds__(256, 2)
void proj_kernel(const bf16* __restrict__ aows, const bf16* __restrict__ wp,
                 const bf16* __restrict__ bp, float* __restrict__ out) {
    __shared__ bf16 As[64][136];
    __shared__ float Csf[64][132];
    __shared__ unsigned int rbo[64];
    const int tid = threadIdx.x;
    const int m0 = blockIdx.x * 64;

    if (tid < 64) {
        int g = m0 + tid;
        int win = g / VOL, tok = g % VOL;
        int b = win >> 7, wi = win & 127;
        int wt_i = wi >> 6, wh_i = (wi >> 3) & 7, ww_i = wi & 7;
        int tt = tok / 49, r2 = tok % 49, hh = r2 / 7, ww2 = r2 % 7;
        int t = wt_i * 8 + tt + STc; if (t >= Tc) t -= Tc;
        int h = wh_i * 7 + hh + SHc; if (h >= Hc) h -= Hc;
        int w = ww_i * 7 + ww2 + SWc; if (w >= Wc) w -= Wc;
        rbo[tid] = (unsigned int)((((b * Tc + t) * Hc + h) * Wc + w) * Cc * 4);
    }
    for (int idx = tid; idx < 64 * 16; idx += 256) {
        int r = idx >> 4, c = idx & 15;
        *(bf16x8*)(&As[r][c * 8]) = *(const bf16x8*)(aows + (size_t)(m0 + r) * Cc + c * 8);
    }
    __syncthreads();

    const int wid = tid >> 6, lane = tid & 63;
    const int quad = lane >> 4, l15 = lane & 15;

    f32x4 acc[8];
#pragma unroll
    for (int nt = 0; nt < 8; ++nt) acc[nt] = zf4();

#pragma unroll
    for (int ko = 0; ko < 4; ++ko) {
        bf16x8 af = *(const bf16x8*)(&As[wid * 16 + l15][ko * 32 + quad * 8]);
#pragma unroll
        for (int nt = 0; nt < 8; ++nt) {
            bf16x8 bfrag = *(const bf16x8*)(wp + (size_t)(nt * 16 + l15) * Cc + ko * 32 + quad * 8);
            acc[nt] = MFMA(af, bfrag, acc[nt]);
        }
    }
#pragma unroll
    for (int nt = 0; nt < 8; ++nt) {
        float bv = (float)bp[nt * 16 + l15];
#pragma unroll
        for (int r = 0; r < 4; ++r) {
            int row = wid * 16 + quad * 4 + r;
            Csf[row][nt * 16 + l15] = acc[nt][r] + bv;
        }
    }
    __syncthreads();

    for (int idx = tid; idx < 64 * 32; idx += 256) {
        int row = idx >> 5, ch = idx & 31;
        float* dst = (float*)((char*)out + rbo[row]) + ch * 4;
        *(f32x4*)dst = *(const f32x4*)(&Csf[row][ch * 4]);
    }
}

extern "C" void kernel_launch(void* const* d_in, const int* in_sizes, int n_in,
                              void* d_out, int out_size, void* d_ws, size_t ws_size,
                              hipStream_t stream) {
    const float* x    = (const float*)d_in[0];
    const float* wqf  = (const float*)d_in[1];
    const float* bqf  = (const float*)d_in[2];
    const float* wpf  = (const float*)d_in[3];
    const float* bpf  = (const float*)d_in[4];
    const float* rpbf = (const float*)d_in[5];
    float* out = (float*)d_out;

    bf16* wqb  = (bf16*)d_ws;              // 49152
    bf16* bqb  = wqb + 49152;              // 384
    bf16* wpb  = bqb + 384;                // 16384
    bf16* bpb  = wpb + 16384;              // 128
    bf16* bmt  = bpb + 128;                // 665600
    bf16* ohq  = bmt + BMT_N;              // 106496
    bf16* ohk  = ohq + OH_N;               // 106496
    bf16* qws  = ohk + OH_N;
    bf16* kws  = qws + QSZ;
    bf16* vws  = kws + QSZ;
    bf16* aows = vws + QSZ;

    hipLaunchKernelGGL(cvt_params, dim3(65), dim3(256), 0, stream,
                       wqf, bqf, wpf, bpf, wqb, bqb, wpb, bpb);
    hipLaunchKernelGGL(biasprep_kernel, dim3((4 * 400 * 104 + 255) / 256), dim3(256), 0, stream,
                       rpbf, bmt);
    hipLaunchKernelGGL(ohprep_kernel, dim3((8 * 416 + 255) / 256), dim3(256), 0, stream,
                       ohq, ohk);
    hipLaunchKernelGGL(qkv_kernel, dim3(MTOT / 64), dim3(256), 0, stream,
                       x, wqb, bqb, qws, kws, vws);
    hipLaunchKernelGGL(attn_kernel, dim3(TWIN * NHc), dim3(512), 0, stream,
                       qws, kws, vws, bmt, ohq, ohk, aows);
    hipLaunchKernelGGL(proj_kernel, dim3(MTOT / 64), dim3(256), 0, stream,
                       aows, wpb, bpb, out);
}

// Round 7
// 255.700 us; speedup vs baseline: 2.0217x; 1.0685x over previous
//
#include <hip/hip_runtime.h>
#include <hip/hip_bf16.h>

typedef __bf16 bf16;
typedef __bf16 bf16x4 __attribute__((ext_vector_type(4)));
typedef __bf16 bf16x8 __attribute__((ext_vector_type(8)));
typedef float f32x4 __attribute__((ext_vector_type(4)));

#define MFMA(a, b, c) __builtin_amdgcn_mfma_f32_16x16x32_bf16(a, b, c, 0, 0, 0)

__device__ inline f32x4 zf4() { return f32x4{0.f, 0.f, 0.f, 0.f}; }

constexpr int Tc = 16, Hc = 56, Wc = 56, Cc = 128, NHc = 4, HDc = 32;
constexpr int VOL = 392;                 // 8*7*7 tokens per window
constexpr int STc = 4, SHc = 3, SWc = 3; // shift
constexpr int TWIN = 256;                // total windows (B * 128)
constexpr int MTOT = TWIN * VOL;         // 100352 tokens
constexpr int QSZ = TWIN * NHc * VOL * HDc;
constexpr int BMT_N = 8 * 4 * 400 * 416; // [pat][head][row][col] bias+mask table

__device__ inline bf16x8 zero8() {
    bf16x8 z;
#pragma unroll
    for (int j = 0; j < 8; ++j) z[j] = (bf16)0.0f;
    return z;
}

__device__ inline f32x4 up4(bf16x4 b) {
    f32x4 r;
#pragma unroll
    for (int j = 0; j < 4; ++j) r[j] = (float)b[j];
    return r;
}

__device__ inline int cls_of(int v, int pt, int ph, int pw) {
    int tt = v / 49, rem = v % 49, hh = rem / 7, ww = rem % 7;
    int ct = pt ? (tt < 4 ? 1 : 2) : 0;
    int ch = ph ? (hh < 4 ? 1 : 2) : 0;
    int cw = pw ? (ww < 4 ? 1 : 2) : 0;
    return ct * 9 + ch * 3 + cw;
}

// ---------------------------------------------------------------------------
// Kernel 0: fused prep. Blocks 0..64: fp32->bf16 param cvt.
// Blocks 65..864: bias+mask table bmt[pat8][head4][row400][col416] bf16 =
//   (rpb + mask)*log2e; pad col -> -144 (exp2 ~ 0), pad row -> 0.
// ---------------------------------------------------------------------------
__global__ void prep_kernel(const float* __restrict__ wq, const float* __restrict__ bq,
                            const float* __restrict__ wp, const float* __restrict__ bp,
                            const float* __restrict__ rpb,
                            bf16* __restrict__ wqb, bf16* __restrict__ bqb,
                            bf16* __restrict__ wpb, bf16* __restrict__ bpb,
                            bf16* __restrict__ bmt) {
    const int blk = blockIdx.x, tid = threadIdx.x;
    if (blk < 65) {
        int i = blk * 256 + tid;
        const float* s; bf16* d; int off;
        if (i < 12288)       { s = wq; d = wqb; off = i; }
        else if (i < 12384)  { s = bq; d = bqb; off = i - 12288; }
        else if (i < 16480)  { s = wp; d = wpb; off = i - 12384; }
        else if (i < 16512)  { s = bp; d = bpb; off = i - 16480; }
        else return;
        f32x4 v = *(const f32x4*)(s + (size_t)off * 4);
        bf16x4 o;
#pragma unroll
        for (int j = 0; j < 4; ++j) o[j] = (bf16)v[j];
        *(bf16x4*)(d + (size_t)off * 4) = o;
        return;
    }
    // bias blocks: bb = (pat, head, rowchunk of 16)
    __shared__ unsigned char clsc[392];
    int bb = blk - 65;
    int pat = bb / 100, rem = bb % 100;
    int head = rem / 25, rc = rem % 25;
    int pt = (pat >> 2) & 1, ph = (pat >> 1) & 1, pw = pat & 1;
    for (int v = tid; v < 392; v += 256) clsc[v] = (unsigned char)cls_of(v, pt, ph, pw);
    __syncthreads();
    bf16* dst = bmt + ((size_t)(pat * NHc + head) * 400 + rc * 16) * 416;
    for (int idx = tid; idx < 16 * 104; idx += 256) {
        int lr = idx / 104, c4 = idx % 104;
        int row = rc * 16 + lr;
        bf16x4 o;
        if (row >= VOL) {
#pragma unroll
            for (int j = 0; j < 4; ++j) o[j] = (bf16)0.f;
        } else {
            int rcls = clsc[row];
            const float* brow = rpb + (size_t)(head * VOL + row) * VOL;
#pragma unroll
            for (int j = 0; j < 4; ++j) {
                int col = c4 * 4 + j;
                float v;
                if (col >= VOL) v = -144.0f;
                else {
                    v = brow[col] * 1.4426950408889634f;
                    if (clsc[col] != rcls) v -= 144.0f;
                }
                o[j] = (bf16)v;
            }
        }
        *(bf16x4*)(dst + (size_t)lr * 416 + c4 * 4) = o;
    }
}

// ---------------------------------------------------------------------------
// Kernel 1: QKV projection (roll+partition fused gather, C^T-layout epilogue:
// lane holds 4 consecutive output cols -> b64 LDS writes).
// q pre-scaled by log2(e)/sqrt(32).
// ---------------------------------------------------------------------------
__global__ __launch_bounds__(256, 2)
void qkv_kernel(const float* __restrict__ x, const bf16* __restrict__ wq,
                const bf16* __restrict__ bq, bf16* __restrict__ qws,
                bf16* __restrict__ kws, bf16* __restrict__ vws) {
    __shared__ bf16 As[64][136];
    __shared__ bf16 Cs[64][396];
    __shared__ unsigned int rb[64];
    __shared__ unsigned int rbw[64];
    const int tid = threadIdx.x;
    const int m0 = blockIdx.x * 64;

    if (tid < 64) {
        int g = m0 + tid;
        int win = g / VOL, tok = g % VOL;
        int b = win >> 7, wi = win & 127;
        int wt_i = wi >> 6, wh_i = (wi >> 3) & 7, ww_i = wi & 7;
        int tt = tok / 49, r2 = tok % 49, hh = r2 / 7, ww2 = r2 % 7;
        int t = wt_i * 8 + tt + STc; if (t >= Tc) t -= Tc;
        int h = wh_i * 7 + hh + SHc; if (h >= Hc) h -= Hc;
        int w = ww_i * 7 + ww2 + SWc; if (w >= Wc) w -= Wc;
        rb[tid] = (unsigned int)((((b * Tc + t) * Hc + h) * Wc + w) * Cc * 4);
        rbw[tid] = (unsigned int)((win << 9) | tok);
    }
    __syncthreads();

    for (int idx = tid; idx < 64 * 32; idx += 256) {
        int r = idx >> 5, c = idx & 31;
        const float* src = (const float*)((const char*)x + rb[r]) + c * 4;
        f32x4 v = *(const f32x4*)src;
        bf16x4 o;
#pragma unroll
        for (int j = 0; j < 4; ++j) o[j] = (bf16)v[j];
        *(bf16x4*)(&As[r][c * 4]) = o;
    }
    __syncthreads();

    const int wid = tid >> 6, lane = tid & 63;
    const int quad = lane >> 4, l15 = lane & 15;
    const int nbase = wid * 96;

    f32x4 acc[6][4];  // [mt = W-col tile][nt = row tile]
#pragma unroll
    for (int mt = 0; mt < 6; ++mt)
#pragma unroll
        for (int nt = 0; nt < 4; ++nt) acc[mt][nt] = zf4();

#pragma unroll
    for (int ko = 0; ko < 4; ++ko) {
        bf16x8 xf[4];  // B-operand: x rows
#pragma unroll
        for (int nt = 0; nt < 4; ++nt)
            xf[nt] = *(const bf16x8*)(&As[nt * 16 + l15][ko * 32 + quad * 8]);
#pragma unroll
        for (int mt = 0; mt < 6; ++mt) {
            bf16x8 wf = *(const bf16x8*)(wq + (size_t)(nbase + mt * 16 + l15) * Cc + ko * 32 + quad * 8);
#pragma unroll
            for (int nt = 0; nt < 4; ++nt)
                acc[mt][nt] = MFMA(wf, xf[nt], acc[mt][nt]);  // C^T: m=col, n=row
        }
    }

#pragma unroll
    for (int mt = 0; mt < 6; ++mt) {
        int colbase = nbase + mt * 16 + quad * 4;
        bf16x4 bc = *(const bf16x4*)(bq + colbase);
        float scale = (colbase < 128) ? 0.25505653942f : 1.0f;  // log2e/sqrt(32) on q
#pragma unroll
        for (int nt = 0; nt < 4; ++nt) {
            bf16x4 o;
#pragma unroll
            for (int r = 0; r < 4; ++r)
                o[r] = (bf16)((acc[mt][nt][r] + (float)bc[r]) * scale);
            *(bf16x4*)(&Cs[nt * 16 + l15][colbase]) = o;
        }
    }
    __syncthreads();

    {
        int row = tid >> 2, hh4 = tid & 3;
        unsigned int p = rbw[row];
        int win = p >> 9, tok = p & 511;
        size_t off = ((size_t)(win * NHc + hh4) * VOL + tok) * HDc;
#pragma unroll
        for (int c = 0; c < 4; ++c) {
            bf16x4 lo = *(const bf16x4*)(&Cs[row][hh4 * 32 + c * 8]);
            bf16x4 hi = *(const bf16x4*)(&Cs[row][hh4 * 32 + c * 8 + 4]);
            *(bf16x8*)(qws + off + c * 8) = __builtin_shufflevector(lo, hi, 0, 1, 2, 3, 4, 5, 6, 7);
        }
#pragma unroll
        for (int c = 0; c < 4; ++c) {
            bf16x4 lo = *(const bf16x4*)(&Cs[row][128 + hh4 * 32 + c * 8]);
            bf16x4 hi = *(const bf16x4*)(&Cs[row][128 + hh4 * 32 + c * 8 + 4]);
            *(bf16x8*)(kws + off + c * 8) = __builtin_shufflevector(lo, hi, 0, 1, 2, 3, 4, 5, 6, 7);
        }
#pragma unroll
        for (int c = 0; c < 4; ++c) {
            bf16x4 lo = *(const bf16x4*)(&Cs[row][256 + hh4 * 32 + c * 8]);
            bf16x4 hi = *(const bf16x4*)(&Cs[row][256 + hh4 * 32 + c * 8 + 4]);
            *(bf16x8*)(vws + off + c * 8) = __builtin_shufflevector(lo, hi, 0, 1, 2, 3, 4, 5, 6, 7);
        }
    }
}

// ---------------------------------------------------------------------------
// Kernel 2: windowed attention, S^T formulation, pattern bias table, PV
// pipelined one kt behind QK. 512 thr/WG, one WG per (win,head), 2 q-tiles/wave.
// ---------------------------------------------------------------------------
__global__ __launch_bounds__(512, 4)
void attn_kernel(const bf16* __restrict__ qws, const bf16* __restrict__ kws,
                 const bf16* __restrict__ vws, const bf16* __restrict__ bmt,
                 bf16* __restrict__ aows) {
    __shared__ bf16 Kl[400][40];      // rows 392..399 zero (kt12 is half-tile)
    __shared__ bf16 Vt[32][424];      // V transposed
    __shared__ bf16 Pb[8][2][16][40]; // per-wave, per-tile P

    const int tid = threadIdx.x;
    const int win = blockIdx.x >> 2, head = blockIdx.x & 3;
    const int wi = win & 127;
    const int wt_i = wi >> 6, wh_i = (wi >> 3) & 7, ww_i = wi & 7;
    const int pat = ((wt_i == 1) << 2) | ((wh_i == 7) << 1) | (ww_i == 7);

    const bf16* Qg = qws + (size_t)(win * NHc + head) * VOL * HDc;
    const bf16* Kg = kws + (size_t)(win * NHc + head) * VOL * HDc;
    const bf16* Vg = vws + (size_t)(win * NHc + head) * VOL * HDc;
    const bf16* Bg = bmt + (size_t)(pat * NHc + head) * 400 * 416;

    for (int idx = tid; idx < 400 * 4; idx += 512) {
        int tok = idx >> 2, c = idx & 3;
        bf16x8 v = zero8();
        if (tok < VOL) v = *(const bf16x8*)(Kg + tok * HDc + c * 8);
        *(bf16x8*)(&Kl[tok][c * 8]) = v;
    }
    if (tid < 416) {  // V transpose: b64 chunks of 4 toks
        int c = tid & 3, tok4 = (tid >> 2) * 4;
        bf16x8 rr[4];
#pragma unroll
        for (int i = 0; i < 4; ++i)
            rr[i] = (tok4 + i < VOL) ? *(const bf16x8*)(Vg + (tok4 + i) * HDc + c * 8) : zero8();
#pragma unroll
        for (int j = 0; j < 8; ++j) {
            bf16x4 wv;
            wv[0] = rr[0][j]; wv[1] = rr[1][j]; wv[2] = rr[2][j]; wv[3] = rr[3][j];
            *(bf16x4*)(&Vt[c * 8 + j][tok4]) = wv;
        }
    }
    __syncthreads();

    const int wid = tid >> 6, lane = tid & 63;
    const int quad = lane >> 4, l15 = lane & 15;
    bf16* PwA = &Pb[wid][0][0][0];
    bf16* PwB = &Pb[wid][1][0][0];

    for (int pass = 0; pass < 2; ++pass) {
        const int qtA = pass * 16 + wid, qtB = qtA + 8;
        const bool hasB = (qtB < 25);
        const int qbA = qtA * 16, qbB = qtB * 16;
        int qrA = qbA + l15; if (qrA >= VOL) qrA = VOL - 1;
        const bf16x8 qfA = *(const bf16x8*)(Qg + (size_t)qrA * HDc + quad * 8);
        const bf16* BrA = Bg + (size_t)(qbA + l15) * 416;
        const bf16* BrB = BrA;
        bf16x8 qfB;
        if (hasB) {
            int qrB = qbB + l15; if (qrB >= VOL) qrB = VOL - 1;
            qfB = *(const bf16x8*)(Qg + (size_t)qrB * HDc + quad * 8);
            BrB = Bg + (size_t)(qbB + l15) * 416;
        }
        f32x4 oA0 = zf4(), oA1 = zf4(), oB0 = zf4(), oB1 = zf4();
        float lsA = 0.f, lsB = 0.f;
        bf16x4 nbA0 = *(const bf16x4*)(BrA + quad * 4);
        bf16x4 nbA1 = *(const bf16x4*)(BrA + 16 + quad * 4);
        bf16x4 nbB0, nbB1;
        if (hasB) {
            nbB0 = *(const bf16x4*)(BrB + quad * 4);
            nbB1 = *(const bf16x4*)(BrB + 16 + quad * 4);
        }

        auto qk_full = [&](int kb) {
            bf16x8 kf0 = *(const bf16x8*)(&Kl[kb + l15][quad * 8]);
            bf16x8 kf1 = *(const bf16x8*)(&Kl[kb + 16 + l15][quad * 8]);
            f32x4 cA0 = up4(nbA0), cA1 = up4(nbA1), cB0, cB1;
            if (hasB) { cB0 = up4(nbB0); cB1 = up4(nbB1); }
            if (kb < 384) {
                nbA0 = *(const bf16x4*)(BrA + kb + 32 + quad * 4);
                nbA1 = *(const bf16x4*)(BrA + kb + 48 + quad * 4);
                if (hasB) {
                    nbB0 = *(const bf16x4*)(BrB + kb + 32 + quad * 4);
                    nbB1 = *(const bf16x4*)(BrB + kb + 48 + quad * 4);
                }
            }
            f32x4 sA0 = MFMA(kf0, qfA, cA0);
            f32x4 sA1 = MFMA(kf1, qfA, cA1);
            bf16x4 pA0, pA1;
            float la = 0.f;
#pragma unroll
            for (int r = 0; r < 4; ++r) {
                float e0 = __builtin_amdgcn_exp2f(sA0[r]);
                float e1 = __builtin_amdgcn_exp2f(sA1[r]);
                pA0[r] = (bf16)e0; pA1[r] = (bf16)e1; la += e0 + e1;
            }
            lsA += la;
            *(bf16x4*)(PwA + l15 * 40 + quad * 4) = pA0;
            *(bf16x4*)(PwA + l15 * 40 + 16 + quad * 4) = pA1;
            if (hasB) {
                f32x4 sB0 = MFMA(kf0, qfB, cB0);
                f32x4 sB1 = MFMA(kf1, qfB, cB1);
                bf16x4 pB0, pB1;
                float lb = 0.f;
#pragma unroll
                for (int r = 0; r < 4; ++r) {
                    float e0 = __builtin_amdgcn_exp2f(sB0[r]);
                    float e1 = __builtin_amdgcn_exp2f(sB1[r]);
                    pB0[r] = (bf16)e0; pB1[r] = (bf16)e1; lb += e0 + e1;
                }
                lsB += lb;
                *(bf16x4*)(PwB + l15 * 40 + quad * 4) = pB0;
                *(bf16x4*)(PwB + l15 * 40 + 16 + quad * 4) = pB1;
            }
        };
        auto pv = [&](int kb) {
            bf16x8 pfA = *(const bf16x8*)(PwA + l15 * 40 + quad * 8);
            bf16x8 pfB;
            if (hasB) pfB = *(const bf16x8*)(PwB + l15 * 40 + quad * 8);
            bf16x8 vf0 = *(const bf16x8*)(&Vt[l15][kb + quad * 8]);
            bf16x8 vf1 = *(const bf16x8*)(&Vt[16 + l15][kb + quad * 8]);
            oA0 = MFMA(vf0, pfA, oA0);
            oA1 = MFMA(vf1, pfA, oA1);
            if (hasB) { oB0 = MFMA(vf0, pfB, oB0); oB1 = MFMA(vf1, pfB, oB1); }
        };

        qk_full(0);
#pragma unroll 1
        for (int kt = 1; kt < 12; ++kt) {
            pv((kt - 1) * 32);   // reads P(kt-1) BEFORE P(kt) writes: WAR-safe (DS in-order)
            qk_full(kt * 32);
        }
        pv(352);
        {   // kt = 12: only first 16-token half is (partially) real
            bf16x8 kf0 = *(const bf16x8*)(&Kl[384 + l15][quad * 8]);
            f32x4 cA0 = up4(nbA0), cB0;
            if (hasB) cB0 = up4(nbB0);
            f32x4 sA0 = MFMA(kf0, qfA, cA0);
            bf16x4 pA0, z4;
            float la = 0.f;
#pragma unroll
            for (int r = 0; r < 4; ++r) {
                float e0 = __builtin_amdgcn_exp2f(sA0[r]);
                pA0[r] = (bf16)e0; la += e0; z4[r] = (bf16)0.f;
            }
            lsA += la;
            *(bf16x4*)(PwA + l15 * 40 + quad * 4) = pA0;
            *(bf16x4*)(PwA + l15 * 40 + 16 + quad * 4) = z4;
            if (hasB) {
                f32x4 sB0 = MFMA(kf0, qfB, cB0);
                bf16x4 pB0;
                float lb = 0.f;
#pragma unroll
                for (int r = 0; r < 4; ++r) {
                    float e0 = __builtin_amdgcn_exp2f(sB0[r]);
                    pB0[r] = (bf16)e0; lb += e0;
                }
                lsB += lb;
                *(bf16x4*)(PwB + l15 * 40 + quad * 4) = pB0;
                *(bf16x4*)(PwB + l15 * 40 + 16 + quad * 4) = z4;
            }
        }
        pv(384);

        lsA += __shfl_xor(lsA, 16); lsA += __shfl_xor(lsA, 32);
        if (hasB) { lsB += __shfl_xor(lsB, 16); lsB += __shfl_xor(lsB, 32); }
        if (qbA + l15 < VOL) {
            float inv = 1.f / lsA;
            bf16x4 w0, w1;
#pragma unroll
            for (int r = 0; r < 4; ++r) { w0[r] = (bf16)(oA0[r] * inv); w1[r] = (bf16)(oA1[r] * inv); }
            bf16* dst = aows + ((size_t)win * VOL + qbA + l15) * Cc + head * HDc;
            *(bf16x4*)(dst + quad * 4) = w0;
            *(bf16x4*)(dst + 16 + quad * 4) = w1;
        }
        if (hasB && qbB + l15 < VOL) {
            float inv = 1.f / lsB;
            bf16x4 w0, w1;
#pragma unroll
            for (int r = 0; r < 4; ++r) { w0[r] = (bf16)(oB0[r] * inv); w1[r] = (bf16)(oB1[r] * inv); }
            bf16* dst = aows + ((size_t)win * VOL + qbB + l15) * Cc + head * HDc;
            *(bf16x4*)(dst + quad * 4) = w0;
            *(bf16x4*)(dst + 16 + quad * 4) = w1;
        }
    }
}

// ---------------------------------------------------------------------------
// Kernel 3: output projection (C^T epilogue: f32x4 b128 LDS writes) +
// un-partition + roll-back scatter, fp32 out.
// ---------------------------------------------------------------------------
__global__ __launch_bounds__(256, 2)
void proj_kernel(const bf16* __restrict__ aows, const bf16* __restrict__ wp,
                 const bf16* __restrict__ bp, float* __restrict__ out) {
    __shared__ bf16 As[64][136];
    __shared__ float Csf[64][132];
    __shared__ unsigned int rbo[64];
    const int tid = threadIdx.x;
    const int m0 = blockIdx.x * 64;

    if (tid < 64) {
        int g = m0 + tid;
        int win = g / VOL, tok = g % VOL;
        int b = win >> 7, wi = win & 127;
        int wt_i = wi >> 6, wh_i = (wi >> 3) & 7, ww_i = wi & 7;
        int tt = tok / 49, r2 = tok % 49, hh = r2 / 7, ww2 = r2 % 7;
        int t = wt_i * 8 + tt + STc; if (t >= Tc) t -= Tc;
        int h = wh_i * 7 + hh + SHc; if (h >= Hc) h -= Hc;
        int w = ww_i * 7 + ww2 + SWc; if (w >= Wc) w -= Wc;
        rbo[tid] = (unsigned int)((((b * Tc + t) * Hc + h) * Wc + w) * Cc * 4);
    }
    for (int idx = tid; idx < 64 * 16; idx += 256) {
        int r = idx >> 4, c = idx & 15;
        *(bf16x8*)(&As[r][c * 8]) = *(const bf16x8*)(aows + (size_t)(m0 + r) * Cc + c * 8);
    }
    __syncthreads();

    const int wid = tid >> 6, lane = tid & 63;
    const int quad = lane >> 4, l15 = lane & 15;

    f32x4 acc[8];  // mt over 128 output cols; rows = wid*16..+15
#pragma unroll
    for (int mt = 0; mt < 8; ++mt) acc[mt] = zf4();

#pragma unroll
    for (int ko = 0; ko < 4; ++ko) {
        bf16x8 xf = *(const bf16x8*)(&As[wid * 16 + l15][ko * 32 + quad * 8]);
#pragma unroll
        for (int mt = 0; mt < 8; ++mt) {
            bf16x8 wf = *(const bf16x8*)(wp + (size_t)(mt * 16 + l15) * Cc + ko * 32 + quad * 8);
            acc[mt] = MFMA(wf, xf, acc[mt]);  // C^T: m=col, n=row
        }
    }
#pragma unroll
    for (int mt = 0; mt < 8; ++mt) {
        int colbase = mt * 16 + quad * 4;
        bf16x4 bc = *(const bf16x4*)(bp + colbase);
        f32x4 o;
#pragma unroll
        for (int r = 0; r < 4; ++r) o[r] = acc[mt][r] + (float)bc[r];
        *(f32x4*)(&Csf[wid * 16 + l15][colbase]) = o;
    }
    __syncthreads();

    for (int idx = tid; idx < 64 * 32; idx += 256) {
        int row = idx >> 5, ch = idx & 31;
        float* dst = (float*)((char*)out + rbo[row]) + ch * 4;
        *(f32x4*)dst = *(const f32x4*)(&Csf[row][ch * 4]);
    }
}

extern "C" void kernel_launch(void* const* d_in, const int* in_sizes, int n_in,
                              void* d_out, int out_size, void* d_ws, size_t ws_size,
                              hipStream_t stream) {
    const float* x    = (const float*)d_in[0];
    const float* wqf  = (const float*)d_in[1];
    const float* bqf  = (const float*)d_in[2];
    const float* wpf  = (const float*)d_in[3];
    const float* bpf  = (const float*)d_in[4];
    const float* rpbf = (const float*)d_in[5];
    float* out = (float*)d_out;

    bf16* wqb  = (bf16*)d_ws;              // 49152
    bf16* bqb  = wqb + 49152;              // 384
    bf16* wpb  = bqb + 384;                // 16384
    bf16* bpb  = wpb + 16384;              // 128
    bf16* bmt  = bpb + 128;                // BMT_N = 5,324,800
    bf16* qws  = bmt + BMT_N;
    bf16* kws  = qws + QSZ;
    bf16* vws  = kws + QSZ;
    bf16* aows = vws + QSZ;

    hipLaunchKernelGGL(prep_kernel, dim3(865), dim3(256), 0, stream,
                       wqf, bqf, wpf, bpf, rpbf, wqb, bqb, wpb, bpb, bmt);
    hipLaunchKernelGGL(qkv_kernel, dim3(MTOT / 64), dim3(256), 0, stream,
                       x, wqb, bqb, qws, kws, vws);
    hipLaunchKernelGGL(attn_kernel, dim3(TWIN * NHc), dim3(512), 0, stream,
                       qws, kws, vws, bmt, aows);
    hipLaunchKernelGGL(proj_kernel, dim3(MTOT / 64), dim3(256), 0, stream,
                       aows, wpb, bpb, out);
}